// Round 1
// 6619.781 us; speedup vs baseline: 6.1689x; 6.1689x over previous
//
#include <hip/hip_runtime.h>

typedef _Float16 f16x8  __attribute__((ext_vector_type(8)));
typedef float    f32x16 __attribute__((ext_vector_type(16)));

#define TSTEPS 500
#define NB 512
#define LOG2E 1.442695041f

// f64 exp, Cody-Waite reduction + degree-11 Taylor, rel err ~1e-15.
__device__ __forceinline__ double exp_d(double v){
  v = fmin(fmax(v, -700.0), 700.0);
  double t = v * 1.4426950408889634;           // v / ln2
  double n = rint(t);
  double f = fma(-n, 6.931471803691238e-01, v);   // LN2_HI
  f = fma(-n, 1.9082149292705877e-10, f);         // LN2_LO
  double p = 2.5052108385441718e-08;           // 1/11!
  p = fma(p, f, 2.7557319223985893e-07);       // 1/10!
  p = fma(p, f, 2.7557319223985888e-06);       // 1/9!
  p = fma(p, f, 2.4801587301587302e-05);       // 1/8!
  p = fma(p, f, 1.9841269841269841e-04);       // 1/7!
  p = fma(p, f, 1.3888888888888889e-03);       // 1/6!
  p = fma(p, f, 8.3333333333333332e-03);       // 1/5!
  p = fma(p, f, 4.1666666666666664e-02);       // 1/4!
  p = fma(p, f, 1.6666666666666666e-01);       // 1/3!
  p = fma(p, f, 0.5);
  p = fma(p, f, 1.0);
  p = fma(p, f, 1.0);
  long long bits = (1023LL + (long long)n) << 52;
  return p * __longlong_as_double(bits);
}

// ---------------------------------------------------------------------------
// Fused GRU, one block of 192 threads per (g,n) sequence.
// Row-per-thread decomposition: thread j owns row j of BOTH W_ih and W_hh
// (32 float4 = 128 VGPRs — fits; the previous 64-thread version demanded
// 384 weight VGPRs and spilled ~130 f32/lane/step to scratch = 25 GB of
// FETCH and 97% stall). h/x broadcast through LDS (uniform-address reads,
// conflict-free); gate math on wave 0 is bit-identical f64 to the passing
// kernel (exp_d ladder, one-shot f16 rounding outside the recurrence).
// ---------------------------------------------------------------------------
__global__ __launch_bounds__(192, 2) void gru_f64(
    const float* __restrict__ x,    // [500,512,64] f32
    const float* __restrict__ st,   // [3,512,64] f32
    const float* __restrict__ wih0, const float* __restrict__ whh0,
    const float* __restrict__ bih0, const float* __restrict__ bhh0,
    const float* __restrict__ wih1, const float* __restrict__ whh1,
    const float* __restrict__ bih1, const float* __restrict__ bhh1,
    const float* __restrict__ wih2, const float* __restrict__ whh2,
    const float* __restrict__ bih2, const float* __restrict__ bhh2,
    _Float16* __restrict__ qkv,      // ws: [3,500,512,64] f16
    float* __restrict__ out_state)   // [3,512,64] f32
{
  __shared__ __align__(16) double hsh[64];
  __shared__ __align__(16) double xsh[64];
  __shared__ __align__(16) double preh[192];
  __shared__ __align__(16) double prex[192];

  const int j    = threadIdx.x;      // row 0..191 (0..63=r, 64..127=z, 128..191=n)
  const int lane = j & 63;
  const int g = blockIdx.x >> 9;
  const int n = blockIdx.x & 511;

  const float* wih = (g==0) ? wih0 : ((g==1) ? wih1 : wih2);
  const float* whh = (g==0) ? whh0 : ((g==1) ? whh1 : whh2);
  const float* bih = (g==0) ? bih0 : ((g==1) ? bih1 : bih2);
  const float* bhh = (g==0) ? bhh0 : ((g==1) ? bhh1 : bhh2);

  // 128 VGPRs: this thread's row of W_ih and W_hh (f32 storage, exact).
  float4 wi[16], wh[16];
  {
    const float4* pi = (const float4*)(wih + (size_t)j*64);
    const float4* ph = (const float4*)(whh + (size_t)j*64);
    #pragma unroll
    for (int q=0;q<16;++q){ wi[q]=pi[q]; wh[q]=ph[q]; }
  }
  const double bi = (double)bih[j];
  const double bh = (double)bhh[j];

  const float* xp = x + (size_t)n*64 + lane;
  _Float16* qout = qkv + ((size_t)g*TSTEPS*NB + n)*64 + lane;

  double h = 0.0;                    // live state only on threads j<64
  float xc0 = 0.f, xc1 = 0.f;        // x prefetch pipeline (wave 0 only)

  if (j < 64){
    h = (double)st[(size_t)(g*512 + n)*64 + j];
    hsh[j] = h;
    xsh[j] = (double)xp[0];          // x[0]
    xc0 = xp[(size_t)NB*64];         // x[1]
    xc1 = xp[(size_t)2*NB*64];       // x[2]
  }
  __syncthreads();

  for (int t=0; t<TSTEPS; ++t){
    // ---- phase A: all 192 threads — two 64-length f64 dot products ----
    double a0=0.0,a1=0.0,a2=0.0,a3=0.0;   // h-dot
    double b0=0.0,b1=0.0,b2=0.0,b3=0.0;   // x-dot
    #pragma unroll
    for (int c4=0;c4<16;++c4){
      double2 h01 = *(const double2*)&hsh[c4*4];
      double2 h23 = *(const double2*)&hsh[c4*4+2];
      double2 x01 = *(const double2*)&xsh[c4*4];
      double2 x23 = *(const double2*)&xsh[c4*4+2];
      float4 w = wh[c4], v = wi[c4];
      a0 = fma((double)w.x, h01.x, a0);
      a1 = fma((double)w.y, h01.y, a1);
      a2 = fma((double)w.z, h23.x, a2);
      a3 = fma((double)w.w, h23.y, a3);
      b0 = fma((double)v.x, x01.x, b0);
      b1 = fma((double)v.y, x01.y, b1);
      b2 = fma((double)v.z, x23.x, b2);
      b3 = fma((double)v.w, x23.y, b3);
    }
    preh[j] = (a0+a2) + (a1+a3) + bh;
    prex[j] = (b0+b2) + (b1+b3) + bi;
    __syncthreads();

    // ---- phase B: wave 0 — gates, state update, outputs, next-x stage ----
    if (j < 64){
      double hr = preh[j],      xr = prex[j];
      double hz = preh[64+j],   xz = prex[64+j];
      double hn = preh[128+j],  xn = prex[128+j];
      double r  = 1.0/(1.0 + exp_d(-(xr + hr)));
      double z  = 1.0/(1.0 + exp_d(-(xz + hz)));
      double yn = xn + r*hn;
      double nn = 1.0 - 2.0/(exp_d(2.0*yn) + 1.0);
      h = (1.0 - z)*nn + z*h;
      hsh[j] = h;
      qout[(size_t)t*NB*64] = (_Float16)(float)h;   // one-shot rounding

      xsh[j] = (double)xc0;                          // x[t+1] for next step
      int tp = (t+3 < TSTEPS) ? (t+3) : (TSTEPS-1);
      float xnx = xp[(size_t)tp*NB*64];
      xc0 = xc1; xc1 = xnx;
    }
    __syncthreads();
  }

  if (j < 64)
    out_state[(size_t)(g*512 + n)*64 + j] = (float)h;
}

// ---------------------------------------------------------------------------
// Attention + output projection (unchanged — output 0 passed with it).
// One wave per (t,b) tile; mfma_f32_32x32x16_f16; f32 output.
// ---------------------------------------------------------------------------
__global__ __launch_bounds__(64) void attn(
    const _Float16* __restrict__ qkv,        // [3,500,512,64] f16
    const float* __restrict__ w_o,           // [64,64] f32
    const float* __restrict__ b_o,           // [64] f32
    float* __restrict__ out)                 // [500,16,32,64] f32
{
  __shared__ __align__(16) _Float16 Qs[32*72];
  __shared__ __align__(16) _Float16 Ks[32*72];
  __shared__ __align__(16) _Float16 Vt[64*40];
  __shared__ __align__(16) _Float16 Wm[32*40];
  __shared__ __align__(16) _Float16 wols[64*72];
  __shared__ float bo[64];

  const int lane = threadIdx.x;
  const int t = blockIdx.x >> 4;
  const int b = blockIdx.x & 15;
  const size_t base    = ((size_t)t*NB + b*32)*64;
  const size_t gstride = (size_t)TSTEPS*NB*64;

  #pragma unroll
  for (int it=0; it<4; ++it){
    int idx = it*64 + lane;
    int f = idx >> 3, ko = (idx & 7)*8;
    *(f16x8*)&Qs[f*72+ko] = *(const f16x8*)&qkv[base + (size_t)f*64 + ko];
    *(f16x8*)&Ks[f*72+ko] = *(const f16x8*)&qkv[gstride + base + (size_t)f*64 + ko];
  }
  #pragma unroll
  for (int it=0; it<32; ++it){
    int idx = it*64 + lane;
    int f = idx >> 6, hh = idx & 63;
    Vt[hh*40 + f] = qkv[2*gstride + base + (size_t)f*64 + hh];
  }
  #pragma unroll
  for (int it=0; it<32; ++it){
    int idx = it*64 + lane;
    int c = idx >> 5, hp = (idx & 31)*2;
    float2 u = *(const float2*)(w_o + c*64 + hp);
    wols[c*72 + hp]     = (_Float16)u.x;
    wols[c*72 + hp + 1] = (_Float16)u.y;
  }
  bo[lane] = b_o[lane];

  const int m  = lane & 31;
  const int hk = (lane >> 5) * 8;
  const int rbase = (lane >> 5) * 4;

  // ---- W = Q @ K^T ----
  f32x16 accW;
  #pragma unroll
  for (int i=0;i<16;++i) accW[i]=0.f;
  #pragma unroll
  for (int kb=0; kb<4; ++kb){
    f16x8 a  = *(const f16x8*)&Qs[m*72 + kb*16 + hk];
    f16x8 bb = *(const f16x8*)&Ks[m*72 + kb*16 + hk];
    accW = __builtin_amdgcn_mfma_f32_32x32x16_f16(a, bb, accW, 0, 0, 0);
  }
  #pragma unroll
  for (int r=0; r<16; ++r){
    int row = (r&3) + 8*(r>>2) + rbase;
    Wm[row*40 + m] = (_Float16)accW[r];
  }

  // ---- A = W @ V ----
  f32x16 accA0, accA1;
  #pragma unroll
  for (int i=0;i<16;++i){ accA0[i]=0.f; accA1[i]=0.f; }
  #pragma unroll
  for (int kb=0; kb<2; ++kb){
    f16x8 a  = *(const f16x8*)&Wm[m*40 + kb*16 + hk];
    f16x8 b0 = *(const f16x8*)&Vt[(     m)*40 + kb*16 + hk];
    f16x8 b1 = *(const f16x8*)&Vt[(32 + m)*40 + kb*16 + hk];
    accA0 = __builtin_amdgcn_mfma_f32_32x32x16_f16(a, b0, accA0, 0, 0, 0);
    accA1 = __builtin_amdgcn_mfma_f32_32x32x16_f16(a, b1, accA1, 0, 0, 0);
  }

  // ---- softmax over f ----
  float mx0 = accA0[0], mx1 = accA1[0];
  #pragma unroll
  for (int r=1;r<16;++r){ mx0 = fmaxf(mx0, accA0[r]); mx1 = fmaxf(mx1, accA1[r]); }
  mx0 = fmaxf(mx0, __shfl_xor(mx0, 32, 64));
  mx1 = fmaxf(mx1, __shfl_xor(mx1, 32, 64));
  float s0 = 0.f, s1 = 0.f;
  #pragma unroll
  for (int r=0;r<16;++r){
    float e0 = __builtin_amdgcn_exp2f(LOG2E*(accA0[r]-mx0)); accA0[r]=e0; s0+=e0;
    float e1 = __builtin_amdgcn_exp2f(LOG2E*(accA1[r]-mx1)); accA1[r]=e1; s1+=e1;
  }
  s0 += __shfl_xor(s0, 32, 64);
  s1 += __shfl_xor(s1, 32, 64);
  float i0 = __builtin_amdgcn_rcpf(s0), i1 = __builtin_amdgcn_rcpf(s1);
  #pragma unroll
  for (int r=0;r<16;++r){
    int row = (r&3) + 8*(r>>2) + rbase;
    Qs[row*72 + m]      = (_Float16)(accA0[r]*i0);
    Qs[row*72 + 32 + m] = (_Float16)(accA1[r]*i1);
  }

  // ---- O = P @ w_o^T + b_o ----
  f32x16 accO0, accO1;
  #pragma unroll
  for (int i=0;i<16;++i){ accO0[i]=0.f; accO1[i]=0.f; }
  #pragma unroll
  for (int kb=0; kb<4; ++kb){
    f16x8 a  = *(const f16x8*)&Qs[m*72 + kb*16 + hk];
    f16x8 b0 = *(const f16x8*)&wols[(     m)*72 + kb*16 + hk];
    f16x8 b1 = *(const f16x8*)&wols[(32 + m)*72 + kb*16 + hk];
    accO0 = __builtin_amdgcn_mfma_f32_32x32x16_f16(a, b0, accO0, 0, 0, 0);
    accO1 = __builtin_amdgcn_mfma_f32_32x32x16_f16(a, b1, accO1, 0, 0, 0);
  }
  const size_t obase = ((size_t)t*16 + b)*2048;
  #pragma unroll
  for (int r=0;r<16;++r){
    int row = (r&3) + 8*(r>>2) + rbase;
    out[obase + row*64 + m]      = accO0[r] + bo[m];
    out[obase + row*64 + 32 + m] = accO1[r] + bo[32+m];
  }
}

// ---------------------------------------------------------------------------
extern "C" void kernel_launch(void* const* d_in, const int* in_sizes, int n_in,
                              void* d_out, int out_size, void* d_ws, size_t ws_size,
                              hipStream_t stream)
{
  const float* x  = (const float*)d_in[0];
  const float* st = (const float*)d_in[1];
  _Float16* qkv = (_Float16*)d_ws;   // 98,304,000 B (fits)
  float* out = (float*)d_out;
  float* out_state = out + (size_t)16384000;

  gru_f64<<<dim3(1536), dim3(192), 0, stream>>>(
    x, st,
    (const float*)d_in[2],  (const float*)d_in[3],
    (const float*)d_in[4],  (const float*)d_in[5],
    (const float*)d_in[6],  (const float*)d_in[7],
    (const float*)d_in[8],  (const float*)d_in[9],
    (const float*)d_in[10], (const float*)d_in[11],
    (const float*)d_in[12], (const float*)d_in[13],
    qkv, out_state);

  attn<<<dim3(8000), dim3(64), 0, stream>>>(
    qkv, (const float*)d_in[14], (const float*)d_in[15], out);
}